// Round 12
// baseline (1295.881 us; speedup 1.0000x reference)
//
#include <hip/hip_runtime.h>
#include <hip/hip_fp16.h>

// Problem constants: B=33 blocks, 8x8 blocks per image, S=8 images.
#define BLKSZ 33
#define NBB   1089   // 33*33
#define IMW   264    // 8*33
#define KPAD  1120   // 35*32, K padded for MFMA

typedef _Float16 f16x8 __attribute__((ext_vector_type(8)));
typedef _Float16 f16x2 __attribute__((ext_vector_type(2)));
typedef float f32x4 __attribute__((ext_vector_type(4)));

__device__ __forceinline__ float dot2f(f16x2 a, f16x2 b, float c) {
#if __has_builtin(__builtin_amdgcn_fdot2)
  return __builtin_amdgcn_fdot2(a, b, c, false);
#else
  return c + (float)a[0] * (float)b[0] + (float)a[1] * (float)b[1];
#endif
}

// ---------------------------------------------------------------------------
// blockify: img [S][264][264] -> X [N=64*S][1089]
__global__ __launch_bounds__(256) void blockify_k(const float* __restrict__ in,
                                                  float* __restrict__ X, int S) {
  int gid = blockIdx.x * 256 + threadIdx.x;
  int total = S * 64 * NBB;
  if (gid >= total) return;
  int n = gid / NBB, p = gid - n * NBB;
  int l = n >> 6, h = (n >> 3) & 7, s = n & 7;
  int i = p / BLKSZ, j = p - i * BLKSZ;
  X[gid] = in[((size_t)s * IMW + h * BLKSZ + i) * IMW + l * BLKSZ + j];
}

// ---------------------------------------------------------------------------
// Split-K NT GEMM partial (setup only)
__global__ __launch_bounds__(256) void gemm_nt_sk(
    const float* __restrict__ Am, const float* __restrict__ Bm,
    float* __restrict__ P, int M, int N, int K, int lda, int ldb, int SK) {
  __shared__ float As[16][68];
  __shared__ float Bs[16][68];
  int tid = threadIdx.x;
  int tx = tid & 15, ty = tid >> 4;
  int bi = blockIdx.y * 64, bj = blockIdx.x * 64;
  int sk = blockIdx.z;
  int chunk = (((K + SK - 1) / SK) + 15) & ~15;
  int kbeg = sk * chunk;
  int kend = kbeg + chunk; if (kend > K) kend = K;
  float acc[4][4] = {{0.f, 0.f, 0.f, 0.f}, {0.f, 0.f, 0.f, 0.f},
                     {0.f, 0.f, 0.f, 0.f}, {0.f, 0.f, 0.f, 0.f}};
  float ra[4], rb[4];
  {
    int kk = kbeg + tx;
#pragma unroll
    for (int t = 0; t < 4; ++t) {
      int r = ty + t * 16;
      ra[t] = (bi + r < M && kk < kend) ? Am[(size_t)(bi + r) * lda + kk] : 0.f;
      rb[t] = (bj + r < N && kk < kend) ? Bm[(size_t)(bj + r) * ldb + kk] : 0.f;
    }
  }
  for (int k0 = kbeg; k0 < kend; k0 += 16) {
#pragma unroll
    for (int t = 0; t < 4; ++t) {
      int r = ty + t * 16;
      As[tx][r] = ra[t];
      Bs[tx][r] = rb[t];
    }
    __syncthreads();
    if (k0 + 16 < kend) {
      int kk = k0 + 16 + tx;
#pragma unroll
      for (int t = 0; t < 4; ++t) {
        int r = ty + t * 16;
        ra[t] = (bi + r < M && kk < kend) ? Am[(size_t)(bi + r) * lda + kk] : 0.f;
        rb[t] = (bj + r < N && kk < kend) ? Bm[(size_t)(bj + r) * ldb + kk] : 0.f;
      }
    }
#pragma unroll
    for (int kk = 0; kk < 16; ++kk) {
      float4 av = *(const float4*)&As[kk][ty * 4];
      float4 bv = *(const float4*)&Bs[kk][tx * 4];
      acc[0][0] += av.x * bv.x; acc[0][1] += av.x * bv.y; acc[0][2] += av.x * bv.z; acc[0][3] += av.x * bv.w;
      acc[1][0] += av.y * bv.x; acc[1][1] += av.y * bv.y; acc[1][2] += av.y * bv.z; acc[1][3] += av.y * bv.w;
      acc[2][0] += av.z * bv.x; acc[2][1] += av.z * bv.y; acc[2][2] += av.z * bv.z; acc[2][3] += av.z * bv.w;
      acc[3][0] += av.w * bv.x; acc[3][1] += av.w * bv.y; acc[3][2] += av.w * bv.z; acc[3][3] += av.w * bv.w;
    }
    __syncthreads();
  }
  size_t base = (size_t)sk * M * N;
#pragma unroll
  for (int r = 0; r < 4; ++r) {
    int i = bi + ty * 4 + r;
    if (i >= M) continue;
#pragma unroll
    for (int c = 0; c < 4; ++c) {
      int j = bj + tx * 4 + c;
      if (j < N) P[base + (size_t)i * N + j] = acc[r][c];
    }
  }
}

// ---------------------------------------------------------------------------
// Reduce split-K partials (setup only). C = sum (and C2 = sum if C2 != null)
__global__ __launch_bounds__(256) void reduce_sk_k(
    const float* __restrict__ P, float* __restrict__ C, float* __restrict__ C2,
    long long total, long long stride, int SK) {
  long long gid = (long long)blockIdx.x * 256 + threadIdx.x;
  if (gid >= total) return;
  float s = 0.f;
  for (int k = 0; k < SK; ++k) s += P[(size_t)k * stride + gid];
  C[gid] = s;
  if (C2) C2[gid] = s;
}

// ---------------------------------------------------------------------------
// Pack conv2-type weights fp32 [co][ci][3][3] -> fp16 [slot][tap][co][ci].
__global__ __launch_bounds__(256) void pack_w_k(const float* __restrict__ w0,
                                                const float* __restrict__ w1,
                                                const float* __restrict__ w2,
                                                const float* __restrict__ w3,
                                                __half* __restrict__ wp, int layers) {
  int gid = blockIdx.x * 256 + threadIdx.x;
  int total = layers * 4 * 9216;
  if (gid >= total) return;
  int slot = gid / 9216, r = gid - slot * 9216;
  int n = slot >> 2, which = slot & 3;
  int tap = r / 1024, r2 = r - tap * 1024;
  int co = r2 >> 5, ci = r2 & 31;
  const float* src = (which == 0) ? w0 : (which == 1) ? w1 : (which == 2) ? w2 : w3;
  wp[gid] = __float2half(src[n * 9216 + (co * 32 + ci) * 9 + tap]);
}

// ---------------------------------------------------------------------------
// Pack AtA fp32 [1089][1089] -> fp16 [1120][1120] zero-padded.
__global__ __launch_bounds__(256) void pack_ata_k(const float* __restrict__ A,
                                                  __half* __restrict__ Ah) {
  int gid = blockIdx.x * 256 + threadIdx.x;
  if (gid >= KPAD * KPAD) return;
  int r = gid / KPAD, c = gid - r * KPAD;
  Ah[gid] = __float2half((r < NBB && c < NBB) ? A[(size_t)r * NBB + c] : 0.f);
}

// ---------------------------------------------------------------------------
// X-update via MFMA fp16: img[unblk(i,j)] = T[i,j] - step*dot(Th[i,:],Ah[j,:]) + step*X0[i,j]
// grid (35, 16), 256 thr = 4 waves, each wave a 16x16 quadrant of the 32x32 tile.
__global__ __launch_bounds__(256) void xupdate_mfma_k(
    const __half* __restrict__ Th, const __half* __restrict__ Ah,
    const float* __restrict__ T, const float* __restrict__ X0,
    float* __restrict__ img, const float* __restrict__ step_ptr) {
  int lane = threadIdx.x & 63;
  int wave = threadIdx.x >> 6;
  int m16 = lane & 15, kg = lane >> 4;
  int i0 = blockIdx.y * 32 + (wave >> 1) * 16;
  int j0 = blockIdx.x * 32 + (wave & 1) * 16;
  const f16x8* ap = (const f16x8*)(Th + (size_t)(i0 + m16) * KPAD + kg * 8);
  const f16x8* bp = (const f16x8*)(Ah + (size_t)(j0 + m16) * KPAD + kg * 8);
  f32x4 acc = {0.f, 0.f, 0.f, 0.f};
  f16x8 a = ap[0], b = bp[0];
#pragma unroll 2
  for (int s = 1; s < 35; ++s) {      // k advances 32 halves = 4 f16x8 per step
    f16x8 an = ap[s * 4];
    f16x8 bn = bp[s * 4];
    acc = __builtin_amdgcn_mfma_f32_16x16x32_f16(a, b, acc, 0, 0, 0);
    a = an; b = bn;
  }
  acc = __builtin_amdgcn_mfma_f32_16x16x32_f16(a, b, acc, 0, 0, 0);
  float st = step_ptr[0];
  int j = j0 + m16;
  if (j < NBB) {
    int pi = j / BLKSZ, pj = j - pi * BLKSZ;
#pragma unroll
    for (int r = 0; r < 4; ++r) {
      int i = i0 + kg * 4 + r;
      size_t idx = (size_t)i * NBB + j;
      float v = T[idx] - st * acc[r] + st * X0[idx];
      int li = i >> 6, hi = (i >> 3) & 7, si = i & 7;
      img[((size_t)si * IMW + hi * BLKSZ + pi) * IMW + li * BLKSZ + pj] = v;
    }
  }
}

// ---------------------------------------------------------------------------
// Zero halo border of ONE NHWC(32) fp16 buffer.
__global__ __launch_bounds__(256) void zero_borders1_k(__half* __restrict__ a,
                                                       int nimg, int H, int W) {
  int Wp = W + 2, Hp = H + 2;
  int perim = 2 * Wp + 2 * H;
  int gid = blockIdx.x * 256 + threadIdx.x;
  int total = nimg * perim;
  if (gid >= total) return;
  int img = gid / perim, k = gid - img * perim;
  int row, col;
  if (k < Wp)            { row = 0;      col = k; }
  else if (k < 2 * Wp)   { row = Hp - 1; col = k - Wp; }
  else { int k2 = k - 2 * Wp; row = 1 + (k2 >> 1); col = (k2 & 1) ? (Wp - 1) : 0; }
  size_t off = ((size_t)(img * Hp + row) * Wp + col) * 32;
  float4 z = {0.f, 0.f, 0.f, 0.f};
  float4* pa = (float4*)(a + off);
#pragma unroll
  for (int q = 0; q < 4; ++q) pa[q] = z;
}

// ---------------------------------------------------------------------------
// conv1: planar fp32 -> padded NHWC fp16, relu(conv+bias). Extended grid:
// border threads write zeros.
__global__ __launch_bounds__(256) void conv1_k(const float* __restrict__ in,
                                               __half* __restrict__ out,
                                               const float* __restrict__ w,
                                               const float* __restrict__ b,
                                               int nimg, int H, int W) {
  __shared__ float wl[9][32];
  __shared__ float bl[32];
  int tid = threadIdx.x;
  for (int t = tid; t < 288; t += 256) {
    int co = t / 9, tap = t - co * 9;
    wl[tap][co] = w[t];
  }
  if (tid < 32) bl[tid] = b[tid];
  __syncthreads();
  int Hp = H + 2, Wp = W + 2;
  int gid = blockIdx.x * 256 + tid;
  if (gid >= nimg * Hp * Wp) return;
  int img = gid / (Hp * Wp);
  int rem = gid - img * (Hp * Wp);
  int yy = rem / Wp, xx = rem - yy * Wp;
  size_t ob = ((size_t)(img * Hp + yy) * Wp + xx) * 32;
  if (yy == 0 || yy == Hp - 1 || xx == 0 || xx == Wp - 1) {
    float4 z = {0.f, 0.f, 0.f, 0.f};
#pragma unroll
    for (int q = 0; q < 4; ++q) *(float4*)(out + ob + 8 * q) = z;
    return;
  }
  int y = yy - 1, x = xx - 1;
  float acc[32];
#pragma unroll
  for (int c = 0; c < 32; ++c) acc[c] = bl[c];
  const float* ip = in + (size_t)img * H * W;
#pragma unroll
  for (int ty = 0; ty < 3; ++ty)
#pragma unroll
    for (int tx = 0; tx < 3; ++tx) {
      int yv = y + ty - 1, xv = x + tx - 1;
      if (yv >= 0 && yv < H && xv >= 0 && xv < W) {
        float v = ip[(size_t)yv * W + xv];
        const float* wp = &wl[ty * 3 + tx][0];
#pragma unroll
        for (int q = 0; q < 8; ++q) {
          float4 wv = *(const float4*)(wp + q * 4);
          acc[q * 4 + 0] += v * wv.x; acc[q * 4 + 1] += v * wv.y;
          acc[q * 4 + 2] += v * wv.z; acc[q * 4 + 3] += v * wv.w;
        }
      }
    }
  __half2* op = (__half2*)(out + ob);
#pragma unroll
  for (int c2 = 0; c2 < 16; ++c2)
    op[c2] = __floats2half2_rn(fmaxf(acc[2 * c2], 0.f), fmaxf(acc[2 * c2 + 1], 0.f));
}

// ---------------------------------------------------------------------------
// conv2 via MFMA, y-marching, BOTH co-halves per wave (A-ring shared, 18 MFMA
// per 3 loads). Wave owns (img, x-tile, y-chunk).
__global__ __launch_bounds__(256) void conv2_mfma_k(const __half* __restrict__ in,
                                                    __half* __restrict__ out,
                                                    const __half* __restrict__ wp,
                                                    const float* __restrict__ bias,
                                                    int nimg, int H, int W, int CH) {
  int ntx = (W + 15) >> 4;
  int nch = (H + CH - 1) / CH;
  int wid = blockIdx.x * 4 + (threadIdx.x >> 6);
  int total = nimg * ntx * nch;
  if (wid >= total) return;
  int lane = threadIdx.x & 63;
  int m16 = lane & 15, kg = lane >> 4;
  int yc = wid % nch; int t = wid / nch;
  int xt = t % ntx; int img = t / ntx;
  int Wp = W + 2, Hp = H + 2, Hpm1 = Hp - 1;
  const __half* wqA = wp + m16 * 32 + kg * 8;
  const __half* wqB = wp + (16 + m16) * 32 + kg * 8;
  f16x8 bA0 = *(const f16x8*)(wqA + 0 * 1024), bB0 = *(const f16x8*)(wqB + 0 * 1024);
  f16x8 bA1 = *(const f16x8*)(wqA + 1 * 1024), bB1 = *(const f16x8*)(wqB + 1 * 1024);
  f16x8 bA2 = *(const f16x8*)(wqA + 2 * 1024), bB2 = *(const f16x8*)(wqB + 2 * 1024);
  f16x8 bA3 = *(const f16x8*)(wqA + 3 * 1024), bB3 = *(const f16x8*)(wqB + 3 * 1024);
  f16x8 bA4 = *(const f16x8*)(wqA + 4 * 1024), bB4 = *(const f16x8*)(wqB + 4 * 1024);
  f16x8 bA5 = *(const f16x8*)(wqA + 5 * 1024), bB5 = *(const f16x8*)(wqB + 5 * 1024);
  f16x8 bA6 = *(const f16x8*)(wqA + 6 * 1024), bB6 = *(const f16x8*)(wqB + 6 * 1024);
  f16x8 bA7 = *(const f16x8*)(wqA + 7 * 1024), bB7 = *(const f16x8*)(wqB + 7 * 1024);
  f16x8 bA8 = *(const f16x8*)(wqA + 8 * 1024), bB8 = *(const f16x8*)(wqB + 8 * 1024);
  float bvA = bias[m16], bvB = bias[16 + m16];
  int x0 = xt << 4;
  int y1 = yc * CH + 1;
  int y2 = y1 + CH - 1; if (y2 > H) y2 = H;
  int c0 = x0 + m16;     if (c0 > W + 1) c0 = W + 1; c0 *= 32;
  int c1 = x0 + m16 + 1; if (c1 > W + 1) c1 = W + 1; c1 *= 32;
  int c2 = x0 + m16 + 2; if (c2 > W + 1) c2 = W + 1; c2 *= 32;
  size_t ibase = (size_t)img * Hp;

#define LOADROW(row, d0, d1, d2) { int rr = (row); if (rr > Hpm1) rr = Hpm1;    \
    const __half* rp = in + (ibase + rr) * (size_t)Wp * 32 + kg * 8;            \
    d0 = *(const f16x8*)(rp + c0); d1 = *(const f16x8*)(rp + c1);               \
    d2 = *(const f16x8*)(rp + c2); }

#define CITER(yo, A0_,A1_,A2_, B0_,B1_,B2_, C0_,C1_,C2_, P0_,P1_,P2_) {         \
    LOADROW((yo) + 3, P0_, P1_, P2_);                                           \
    f32x4 aA0 = {0.f,0.f,0.f,0.f}, aA1 = {0.f,0.f,0.f,0.f};                     \
    f32x4 aB0 = {0.f,0.f,0.f,0.f}, aB1 = {0.f,0.f,0.f,0.f};                     \
    aA0 = __builtin_amdgcn_mfma_f32_16x16x32_f16(A0_, bA0, aA0, 0, 0, 0);       \
    aB0 = __builtin_amdgcn_mfma_f32_16x16x32_f16(A0_, bB0, aB0, 0, 0, 0);       \
    aA1 = __builtin_amdgcn_mfma_f32_16x16x32_f16(A1_, bA1, aA1, 0, 0, 0);       \
    aB1 = __builtin_amdgcn_mfma_f32_16x16x32_f16(A1_, bB1, aB1, 0, 0, 0);       \
    aA0 = __builtin_amdgcn_mfma_f32_16x16x32_f16(A2_, bA2, aA0, 0, 0, 0);       \
    aB0 = __builtin_amdgcn_mfma_f32_16x16x32_f16(A2_, bB2, aB0, 0, 0, 0);       \
    aA1 = __builtin_amdgcn_mfma_f32_16x16x32_f16(B0_, bA3, aA1, 0, 0, 0);       \
    aB1 = __builtin_amdgcn_mfma_f32_16x16x32_f16(B0_, bB3, aB1, 0, 0, 0);       \
    aA0 = __builtin_amdgcn_mfma_f32_16x16x32_f16(B1_, bA4, aA0, 0, 0, 0);       \
    aB0 = __builtin_amdgcn_mfma_f32_16x16x32_f16(B1_, bB4, aB0, 0, 0, 0);       \
    aA1 = __builtin_amdgcn_mfma_f32_16x16x32_f16(B2_, bA5, aA1, 0, 0, 0);       \
    aB1 = __builtin_amdgcn_mfma_f32_16x16x32_f16(B2_, bB5, aB1, 0, 0, 0);       \
    aA0 = __builtin_amdgcn_mfma_f32_16x16x32_f16(C0_, bA6, aA0, 0, 0, 0);       \
    aB0 = __builtin_amdgcn_mfma_f32_16x16x32_f16(C0_, bB6, aB0, 0, 0, 0);       \
    aA1 = __builtin_amdgcn_mfma_f32_16x16x32_f16(C1_, bA7, aA1, 0, 0, 0);       \
    aB1 = __builtin_amdgcn_mfma_f32_16x16x32_f16(C1_, bB7, aB1, 0, 0, 0);       \
    aA0 = __builtin_amdgcn_mfma_f32_16x16x32_f16(C2_, bA8, aA0, 0, 0, 0);       \
    aB0 = __builtin_amdgcn_mfma_f32_16x16x32_f16(C2_, bB8, aB0, 0, 0, 0);       \
    __half* op = out + (ibase + (yo)) * (size_t)Wp * 32;                        \
    _Pragma("unroll")                                                           \
    for (int r = 0; r < 4; ++r) { int xo = x0 + kg * 4 + r;                     \
      if (xo < W) { __half* o2 = op + (xo + 1) * 32;                            \
        o2[m16]      = __float2half(fmaxf(aA0[r] + aA1[r] + bvA, 0.f));         \
        o2[16 + m16] = __float2half(fmaxf(aB0[r] + aB1[r] + bvB, 0.f)); } } }

  f16x8 A0,A1,A2,B0,B1,B2,C0,C1,C2,D0,D1,D2,E0,E1,E2;
  LOADROW(y1 - 1, A0, A1, A2);
  LOADROW(y1,     B0, B1, B2);
  LOADROW(y1 + 1, C0, C1, C2);
  LOADROW(y1 + 2, D0, D1, D2);
  int yo = y1;
  for (; yo + 4 <= y2; yo += 5) {
    CITER(yo,     A0,A1,A2, B0,B1,B2, C0,C1,C2, E0,E1,E2);
    CITER(yo + 1, B0,B1,B2, C0,C1,C2, D0,D1,D2, A0,A1,A2);
    CITER(yo + 2, C0,C1,C2, D0,D1,D2, E0,E1,E2, B0,B1,B2);
    CITER(yo + 3, D0,D1,D2, E0,E1,E2, A0,A1,A2, C0,C1,C2);
    CITER(yo + 4, E0,E1,E2, A0,A1,A2, B0,B1,B2, D0,D1,D2);
  }
  if (yo <= y2) { CITER(yo, A0,A1,A2, B0,B1,B2, C0,C1,C2, E0,E1,E2); ++yo; }
  if (yo <= y2) { CITER(yo, B0,B1,B2, C0,C1,C2, D0,D1,D2, A0,A1,A2); ++yo; }
  if (yo <= y2) { CITER(yo, C0,C1,C2, D0,D1,D2, E0,E1,E2, B0,B1,B2); ++yo; }
  if (yo <= y2) { CITER(yo, D0,D1,D2, E0,E1,E2, A0,A1,A2, C0,C1,C2); ++yo; }
#undef CITER
#undef LOADROW
}

// ---------------------------------------------------------------------------
// conv4: padded NHWC fp16 -> fp32 via fdot2. out = src + sign*conv.
// perm=1: blockify write.
__global__ __launch_bounds__(256) void conv4_k(const __half* __restrict__ in,
                                               float* __restrict__ out,
                                               const float* __restrict__ w,
                                               const float* __restrict__ src,
                                               int nimg, int H, int W, float sign, int perm) {
  __shared__ f16x2 wl[9][16];   // [tap][ci-pair]
  int tid = threadIdx.x;
  for (int t = tid; t < 144; t += 256) {
    int tap = t % 9, c2 = t / 9;
    f16x2 h;
    h[0] = (_Float16)w[(2 * c2) * 9 + tap];
    h[1] = (_Float16)w[(2 * c2 + 1) * 9 + tap];
    wl[tap][c2] = h;
  }
  __syncthreads();
  int gid = blockIdx.x * 256 + tid;
  if (gid >= nimg * H * W) return;
  int img = gid / (H * W);
  int rem = gid - img * H * W;
  int y = rem / W, x = rem - y * W;
  int Wp = W + 2;
  float acc = 0.f;
#pragma unroll
  for (int ty = 0; ty < 3; ++ty)
#pragma unroll
    for (int tx = 0; tx < 3; ++tx) {
      const f16x8* ip = (const f16x8*)(in + ((size_t)(img * (H + 2) + y + ty) * Wp + x + tx) * 32);
      const f16x2* wpt = &wl[ty * 3 + tx][0];
#pragma unroll
      for (int q = 0; q < 4; ++q) {
        f16x8 v = ip[q];
        const f16x2* pv = (const f16x2*)&v;
#pragma unroll
        for (int e = 0; e < 4; ++e) acc = dot2f(pv[e], wpt[q * 4 + e], acc);
      }
    }
  float val = src[gid] + sign * acc;
  if (perm) {
    int h = y / BLKSZ, i = y - h * BLKSZ;
    int l = x / BLKSZ, j = x - l * BLKSZ;
    out[(size_t)(l * 64 + h * 8 + img) * NBB + i * BLKSZ + j] = val;
  } else {
    out[gid] = val;
  }
}

// ---------------------------------------------------------------------------
// FUSED denoise CNN: one workgroup (8 waves, 512 thr) per 33x33 image; both
// padded 35x35x32 fp16 planes in LDS. Emits T = X + noise (fp32 + fp16 padded).
// __launch_bounds__(512, 2): min 2 waves/EU -> VGPR cap 256 (kernel needs ~190;
// round 10's plain (512) capped at 128 -> scratch spill, 133MB HBM traffic).
__global__ __launch_bounds__(512, 2) void denoise_fused_k(
    const float* __restrict__ X, float* __restrict__ T, __half* __restrict__ Th,
    const float* __restrict__ w1, const float* __restrict__ b1,
    const __half* __restrict__ wp2, const float* __restrict__ b2,
    const __half* __restrict__ wp3, const float* __restrict__ b3,
    const float* __restrict__ w4) {
  __shared__ __align__(16) __half Abuf[35 * 35 * 32];   // 78400 B
  __shared__ __align__(16) __half Bbuf[35 * 35 * 32];   // 78400 B
  __shared__ float wl1[9][32];
  __shared__ f16x2 wl4h[9][16];
  __shared__ float bl1[32];
  int tid = threadIdx.x;
  int img = blockIdx.x;
  int wave = tid >> 6, lane = tid & 63;
  int m16 = lane & 15, kg = lane >> 4;

  for (int t = tid; t < 288; t += 512) {
    int c = t / 9, tap = t - c * 9;
    wl1[tap][c] = w1[t];
  }
  for (int t = tid; t < 144; t += 512) {
    int tap = t % 9, c2 = t / 9;
    f16x2 h;
    h[0] = (_Float16)w4[(2 * c2) * 9 + tap];
    h[1] = (_Float16)w4[(2 * c2 + 1) * 9 + tap];
    wl4h[tap][c2] = h;
  }
  if (tid < 32) bl1[tid] = b1[tid];
  // stage X image into Bbuf-front (dead after conv1)
  float* Xs = (float*)Bbuf;
  const float* Xg = X + (size_t)img * NBB;
  for (int t = tid; t < NBB; t += 512) Xs[t] = Xg[t];
  __syncthreads();

  // ---- phase 1: conv1  Xs -> Abuf (padded, borders zeroed) ----
  for (int cell = tid; cell < 1225; cell += 512) {
    int yy = cell / 35, xx = cell - yy * 35;
    __half* oc = Abuf + cell * 32;
    if (yy == 0 || yy == 34 || xx == 0 || xx == 34) {
      f16x8 hz = {};
#pragma unroll
      for (int q = 0; q < 4; ++q) *(f16x8*)(oc + 8 * q) = hz;
      continue;
    }
    int y = yy - 1, x = xx - 1;
    float acc[32];
#pragma unroll
    for (int c = 0; c < 32; ++c) acc[c] = bl1[c];
#pragma unroll
    for (int dy = 0; dy < 3; ++dy)
#pragma unroll
      for (int dx = 0; dx < 3; ++dx) {
        int yv = y + dy - 1, xv = x + dx - 1;
        if (yv >= 0 && yv < 33 && xv >= 0 && xv < 33) {
          float v = Xs[yv * 33 + xv];
          const float* wp = &wl1[dy * 3 + dx][0];
#pragma unroll
          for (int q = 0; q < 8; ++q) {
            float4 wv = *(const float4*)(wp + q * 4);
            acc[q * 4 + 0] += v * wv.x; acc[q * 4 + 1] += v * wv.y;
            acc[q * 4 + 2] += v * wv.z; acc[q * 4 + 3] += v * wv.w;
          }
        }
      }
    __half2* op = (__half2*)oc;
#pragma unroll
    for (int c2 = 0; c2 < 16; ++c2)
      op[c2] = __floats2half2_rn(fmaxf(acc[2 * c2], 0.f), fmaxf(acc[2 * c2 + 1], 0.f));
  }
  __syncthreads();

  // ---- conv2 over LDS: 24 jobs = cohalf(2) x xt(3) x yh(4 chunks of 9) ----
#define CONV2LDS(SRC, DST, WPTR, BPTR) {                                        \
  _Pragma("unroll 1")                                                           \
  for (int jid = wave; jid < 24; jid += 8) {                                    \
    int cohalf = jid & 1;                                                       \
    int xt = (jid >> 1) % 3;                                                    \
    int yh = jid / 6;                                                           \
    const __half* wq = WPTR + (cohalf * 16 + m16) * 32 + kg * 8;                \
    f16x8 bfr0 = *(const f16x8*)(wq + 0 * 1024);                                \
    f16x8 bfr1 = *(const f16x8*)(wq + 1 * 1024);                                \
    f16x8 bfr2 = *(const f16x8*)(wq + 2 * 1024);                                \
    f16x8 bfr3 = *(const f16x8*)(wq + 3 * 1024);                                \
    f16x8 bfr4 = *(const f16x8*)(wq + 4 * 1024);                                \
    f16x8 bfr5 = *(const f16x8*)(wq + 5 * 1024);                                \
    f16x8 bfr6 = *(const f16x8*)(wq + 6 * 1024);                                \
    f16x8 bfr7 = *(const f16x8*)(wq + 7 * 1024);                                \
    f16x8 bfr8 = *(const f16x8*)(wq + 8 * 1024);                                \
    float bv = BPTR[cohalf * 16 + m16];                                         \
    int x0 = xt << 4;                                                           \
    int y1 = 1 + yh * 9;                                                        \
    int y2 = y1 + 8; if (y2 > 33) y2 = 33;                                      \
    int c0 = x0 + m16;     if (c0 > 34) c0 = 34; c0 *= 32;                      \
    int c1 = x0 + m16 + 1; if (c1 > 34) c1 = 34; c1 *= 32;                      \
    int c2 = x0 + m16 + 2; if (c2 > 34) c2 = 34; c2 *= 32;                      \
    int cohalf16 = cohalf * 16;                                                 \
    f16x8 A0,A1,A2,B0,B1,B2,C0,C1,C2,D0,D1,D2,E0,E1,E2;                         \
    LROW(SRC, y1 - 1, A0, A1, A2);                                              \
    LROW(SRC, y1,     B0, B1, B2);                                              \
    LROW(SRC, y1 + 1, C0, C1, C2);                                              \
    LROW(SRC, y1 + 2, D0, D1, D2);                                              \
    int yo = y1;                                                                \
    for (; yo + 4 <= y2; yo += 5) {                                             \
      CIT(SRC, DST, yo,     A0,A1,A2, B0,B1,B2, C0,C1,C2, E0,E1,E2);            \
      CIT(SRC, DST, yo + 1, B0,B1,B2, C0,C1,C2, D0,D1,D2, A0,A1,A2);            \
      CIT(SRC, DST, yo + 2, C0,C1,C2, D0,D1,D2, E0,E1,E2, B0,B1,B2);            \
      CIT(SRC, DST, yo + 3, D0,D1,D2, E0,E1,E2, A0,A1,A2, C0,C1,C2);            \
      CIT(SRC, DST, yo + 4, E0,E1,E2, A0,A1,A2, B0,B1,B2, D0,D1,D2);            \
    }                                                                           \
    if (yo <= y2) { CIT(SRC, DST, yo, A0,A1,A2, B0,B1,B2, C0,C1,C2, E0,E1,E2); ++yo; } \
    if (yo <= y2) { CIT(SRC, DST, yo, B0,B1,B2, C0,C1,C2, D0,D1,D2, A0,A1,A2); ++yo; } \
    if (yo <= y2) { CIT(SRC, DST, yo, C0,C1,C2, D0,D1,D2, E0,E1,E2, B0,B1,B2); ++yo; } \
    if (yo <= y2) { CIT(SRC, DST, yo, D0,D1,D2, E0,E1,E2, A0,A1,A2, C0,C1,C2); ++yo; } \
  } }

#define LROW(SRC, row, d0, d1, d2) { int rr = (row); if (rr > 34) rr = 34;      \
    const __half* rp = SRC + rr * 35 * 32 + kg * 8;                             \
    d0 = *(const f16x8*)(rp + c0); d1 = *(const f16x8*)(rp + c1);               \
    d2 = *(const f16x8*)(rp + c2); }

#define CIT(SRC, DST, yo, A0_,A1_,A2_, B0_,B1_,B2_, C0_,C1_,C2_, P0_,P1_,P2_) { \
    LROW(SRC, (yo) + 3, P0_, P1_, P2_);                                         \
    f32x4 a0 = {0.f, 0.f, 0.f, 0.f}, a1 = {0.f, 0.f, 0.f, 0.f};                 \
    a0 = __builtin_amdgcn_mfma_f32_16x16x32_f16(A0_, bfr0, a0, 0, 0, 0);        \
    a1 = __builtin_amdgcn_mfma_f32_16x16x32_f16(A1_, bfr1, a1, 0, 0, 0);        \
    a0 = __builtin_amdgcn_mfma_f32_16x16x32_f16(A2_, bfr2, a0, 0, 0, 0);        \
    a1 = __builtin_amdgcn_mfma_f32_16x16x32_f16(B0_, bfr3, a1, 0, 0, 0);        \
    a0 = __builtin_amdgcn_mfma_f32_16x16x32_f16(B1_, bfr4, a0, 0, 0, 0);        \
    a1 = __builtin_amdgcn_mfma_f32_16x16x32_f16(B2_, bfr5, a1, 0, 0, 0);        \
    a0 = __builtin_amdgcn_mfma_f32_16x16x32_f16(C0_, bfr6, a0, 0, 0, 0);        \
    a1 = __builtin_amdgcn_mfma_f32_16x16x32_f16(C1_, bfr7, a1, 0, 0, 0);        \
    a0 = __builtin_amdgcn_mfma_f32_16x16x32_f16(C2_, bfr8, a0, 0, 0, 0);        \
    _Pragma("unroll")                                                           \
    for (int r = 0; r < 4; ++r) { int xo = x0 + kg * 4 + r;                     \
      if (xo < 33) DST[(yo) * 35 * 32 + (xo + 1) * 32 + cohalf16 + m16] =       \
        __float2half(fmaxf(a0[r] + a1[r] + bv, 0.f)); } }

  // ---- phase 2: zero Bbuf borders, then conv2#1  Abuf -> Bbuf ----
  {
    f16x8 hz = {};
    for (int t = tid; t < 544; t += 512) {
      int ci = t >> 2, q = t & 3;
      int cell;
      if (ci < 35)       cell = ci;
      else if (ci < 70)  cell = 34 * 35 + (ci - 35);
      else if (ci < 103) cell = (ci - 70 + 1) * 35;
      else               cell = (ci - 103 + 1) * 35 + 34;
      *(f16x8*)(Bbuf + cell * 32 + q * 8) = hz;
    }
  }
  __syncthreads();
  CONV2LDS(Abuf, Bbuf, wp2, b2);
  __syncthreads();

  // ---- phase 3: conv2#2  Bbuf -> Abuf (interior; Abuf halo still zero) ----
  CONV2LDS(Bbuf, Abuf, wp3, b3);
  __syncthreads();
#undef CIT
#undef LROW
#undef CONV2LDS

  // ---- phase 4: conv4 via fdot2  Abuf -> T = X + noise (fp32 + fp16 copy) ----
  float* Tg = T + (size_t)img * NBB;
  __half* Thg = Th + (size_t)img * KPAD;
  for (int p = tid; p < NBB; p += 512) {
    int y = p / 33, x = p - y * 33;
    float acc = 0.f;
#pragma unroll
    for (int dy = 0; dy < 3; ++dy)
#pragma unroll
      for (int dx = 0; dx < 3; ++dx) {
        const f16x8* ip = (const f16x8*)(Abuf + ((y + dy) * 35 + x + dx) * 32);
        const f16x2* wpt = &wl4h[dy * 3 + dx][0];
#pragma unroll
        for (int q = 0; q < 4; ++q) {
          f16x8 v = ip[q];
          const f16x2* pv = (const f16x2*)&v;
#pragma unroll
          for (int e = 0; e < 4; ++e) acc = dot2f(pv[e], wpt[q * 4 + e], acc);
        }
      }
    float val = Xg[p] + acc;
    Tg[p] = val;
    Thg[p] = __float2half(val);
  }
  for (int t = tid; t < KPAD - NBB; t += 512)
    Thg[NBB + t] = __float2half(0.f);
}

// ---------------------------------------------------------------------------
static inline int cdiv(int a, int b) { return (a + b - 1) / b; }

extern "C" void kernel_launch(void* const* d_in, const int* in_sizes, int n_in,
                              void* d_out, int out_size, void* d_ws, size_t ws_size,
                              hipStream_t stream) {
  const float* d_inputs = (const float*)d_in[0];
  const float* d_A      = (const float*)d_in[1];
  const float* d_Q      = (const float*)d_in[2];
  const float* d_steps  = (const float*)d_in[3];
  const float* den_w1 = (const float*)d_in[4];
  const float* den_b1 = (const float*)d_in[5];
  const float* den_b2 = (const float*)d_in[7];
  const float* den_b3 = (const float*)d_in[9];
  const float* den_w4 = (const float*)d_in[10];
  const float* deb_w1 = (const float*)d_in[11];
  const float* deb_b1 = (const float*)d_in[12];
  const float* deb_b2 = (const float*)d_in[14];
  const float* deb_b3 = (const float*)d_in[16];
  const float* deb_w4 = (const float*)d_in[17];

  int layers = in_sizes[3];                 // 5
  int M      = in_sizes[1] / NBB;           // 272
  int S      = in_sizes[0] / (IMW * IMW);   // 8
  int N      = 64 * S;                      // 512

  // ---- workspace layout ----
  float* ws    = (float*)d_ws;
  float* AtA   = ws;                           // 1089*1089 (pad 1185936)
  float* X     = AtA + 1185936;                // [N][1089]
  float* T     = X + (size_t)N * NBB;          // [N][1089]
  float* X0    = T + (size_t)N * NBB;          // [N][1089]
  float* y2    = X0 + (size_t)N * NBB;         // [N][M]
  float* img   = y2 + (size_t)N * M;           // [S][264][264]
  float* Pbuf  = img + (size_t)S * IMW * IMW;  // split-K partials (setup)
  __half* wph  = (__half*)(Pbuf + (size_t)8 * N * NBB);
  __half* buf1 = wph + (size_t)layers * 4 * 9216 + 2048;
  size_t bufElems = (size_t)S * 266 * 266 * 32;
  __half* buf2 = buf1 + bufElems;
  __half* Ah   = buf2 + bufElems;              // [1120][1120] fp16
  __half* Th   = Ah + (size_t)KPAD * KPAD;     // [N][1120] fp16

  dim3 blk(256);

  // ---- setup ----
  pack_w_k<<<cdiv(layers * 4 * 9216, 256), blk, 0, stream>>>(
      (const float*)d_in[6], (const float*)d_in[8], (const float*)d_in[13],
      (const float*)d_in[15], wph, layers);
  blockify_k<<<cdiv(N * NBB, 256), blk, 0, stream>>>(d_inputs, T, S);  // T = Xb

  gemm_nt_sk<<<dim3(cdiv(NBB, 64), cdiv(NBB, 64), 2), blk, 0, stream>>>(
      d_Q, d_Q, Pbuf, NBB, NBB, M, M, M, 2);
  reduce_sk_k<<<cdiv(NBB * NBB, 256), blk, 0, stream>>>(
      Pbuf, AtA, nullptr, (long long)NBB * NBB, (long long)NBB * NBB, 2);
  pack_ata_k<<<cdiv(KPAD * KPAD, 256), blk, 0, stream>>>(AtA, Ah);
  gemm_nt_sk<<<dim3(cdiv(M, 64), cdiv(N, 64), 8), blk, 0, stream>>>(
      T, d_A, Pbuf, N, M, NBB, NBB, NBB, 8);
  reduce_sk_k<<<cdiv(N * M, 256), blk, 0, stream>>>(
      Pbuf, y2, nullptr, (long long)N * M, (long long)N * M, 8);
  gemm_nt_sk<<<dim3(cdiv(NBB, 64), cdiv(N, 64), 4), blk, 0, stream>>>(
      y2, d_Q, Pbuf, N, NBB, M, M, M, 4);
  reduce_sk_k<<<cdiv(N * NBB, 256), blk, 0, stream>>>(
      Pbuf, X0, X, (long long)N * NBB, (long long)N * NBB, 4);

  const int CH_DEB = 12;
  int deb_jobs = S * cdiv(IMW, 16) * cdiv(IMW, CH_DEB);   // 8*17*22

  for (int n = 0; n < layers; ++n) {
    const float* stepp = d_steps + n;

    // ---- denoise CNN (fused, LDS-resident, 8 waves): T = X + noise ----
    denoise_fused_k<<<N, dim3(512), 0, stream>>>(
        X, T, Th, den_w1 + n * 288, den_b1 + n * 32,
        wph + (size_t)(n * 4 + 0) * 9216, den_b2 + n * 32,
        wph + (size_t)(n * 4 + 1) * 9216, den_b3 + n * 32,
        den_w4 + n * 288);

    // ---- img = unblockify( T - step*(T@AtA) + step*X0 )  [MFMA fp16] ----
    xupdate_mfma_k<<<dim3(35, 16), blk, 0, stream>>>(
        Th, Ah, T, X0, img, stepp);

    // ---- deblock CNN on img ----
    zero_borders1_k<<<cdiv(S * (2 * 266 + 2 * 264), 256), blk, 0, stream>>>(
        buf2, S, IMW, IMW);
    conv1_k<<<cdiv(S * 266 * 266, 256), blk, 0, stream>>>(
        img, buf1, deb_w1 + n * 288, deb_b1 + n * 32, S, IMW, IMW);
    conv2_mfma_k<<<cdiv(deb_jobs, 4), blk, 0, stream>>>(
        buf1, buf2, wph + (size_t)(n * 4 + 2) * 9216, deb_b2 + n * 32, S, IMW, IMW, CH_DEB);
    conv2_mfma_k<<<cdiv(deb_jobs, 4), blk, 0, stream>>>(
        buf2, buf1, wph + (size_t)(n * 4 + 3) * 9216, deb_b3 + n * 32, S, IMW, IMW, CH_DEB);
    if (n < layers - 1) {
      conv4_k<<<cdiv(S * IMW * IMW, 256), blk, 0, stream>>>(
          buf1, X, deb_w4 + n * 288, img, S, IMW, IMW, -1.f, 1);
    } else {
      conv4_k<<<cdiv(S * IMW * IMW, 256), blk, 0, stream>>>(
          buf1, (float*)d_out, deb_w4 + n * 288, img, S, IMW, IMW, -1.f, 0);
    }
  }
}

// Round 13
// 1073.310 us; speedup vs baseline: 1.2074x; 1.2074x over previous
//
#include <hip/hip_runtime.h>
#include <hip/hip_fp16.h>

// Problem constants: B=33 blocks, 8x8 blocks per image, S=8 images.
#define BLKSZ 33
#define NBB   1089   // 33*33
#define IMW   264    // 8*33
#define KPAD  1120   // 35*32, K padded for MFMA

typedef _Float16 f16x8 __attribute__((ext_vector_type(8)));
typedef _Float16 f16x2 __attribute__((ext_vector_type(2)));
typedef float f32x4 __attribute__((ext_vector_type(4)));

__device__ __forceinline__ float dot2f(f16x2 a, f16x2 b, float c) {
#if __has_builtin(__builtin_amdgcn_fdot2)
  return __builtin_amdgcn_fdot2(a, b, c, false);
#else
  return c + (float)a[0] * (float)b[0] + (float)a[1] * (float)b[1];
#endif
}

// ---------------------------------------------------------------------------
// blockify: img [S][264][264] -> X [N=64*S][1089]
__global__ __launch_bounds__(256) void blockify_k(const float* __restrict__ in,
                                                  float* __restrict__ X, int S) {
  int gid = blockIdx.x * 256 + threadIdx.x;
  int total = S * 64 * NBB;
  if (gid >= total) return;
  int n = gid / NBB, p = gid - n * NBB;
  int l = n >> 6, h = (n >> 3) & 7, s = n & 7;
  int i = p / BLKSZ, j = p - i * BLKSZ;
  X[gid] = in[((size_t)s * IMW + h * BLKSZ + i) * IMW + l * BLKSZ + j];
}

// ---------------------------------------------------------------------------
// Split-K NT GEMM partial (setup only)
__global__ __launch_bounds__(256) void gemm_nt_sk(
    const float* __restrict__ Am, const float* __restrict__ Bm,
    float* __restrict__ P, int M, int N, int K, int lda, int ldb, int SK) {
  __shared__ float As[16][68];
  __shared__ float Bs[16][68];
  int tid = threadIdx.x;
  int tx = tid & 15, ty = tid >> 4;
  int bi = blockIdx.y * 64, bj = blockIdx.x * 64;
  int sk = blockIdx.z;
  int chunk = (((K + SK - 1) / SK) + 15) & ~15;
  int kbeg = sk * chunk;
  int kend = kbeg + chunk; if (kend > K) kend = K;
  float acc[4][4] = {{0.f, 0.f, 0.f, 0.f}, {0.f, 0.f, 0.f, 0.f},
                     {0.f, 0.f, 0.f, 0.f}, {0.f, 0.f, 0.f, 0.f}};
  float ra[4], rb[4];
  {
    int kk = kbeg + tx;
#pragma unroll
    for (int t = 0; t < 4; ++t) {
      int r = ty + t * 16;
      ra[t] = (bi + r < M && kk < kend) ? Am[(size_t)(bi + r) * lda + kk] : 0.f;
      rb[t] = (bj + r < N && kk < kend) ? Bm[(size_t)(bj + r) * ldb + kk] : 0.f;
    }
  }
  for (int k0 = kbeg; k0 < kend; k0 += 16) {
#pragma unroll
    for (int t = 0; t < 4; ++t) {
      int r = ty + t * 16;
      As[tx][r] = ra[t];
      Bs[tx][r] = rb[t];
    }
    __syncthreads();
    if (k0 + 16 < kend) {
      int kk = k0 + 16 + tx;
#pragma unroll
      for (int t = 0; t < 4; ++t) {
        int r = ty + t * 16;
        ra[t] = (bi + r < M && kk < kend) ? Am[(size_t)(bi + r) * lda + kk] : 0.f;
        rb[t] = (bj + r < N && kk < kend) ? Bm[(size_t)(bj + r) * ldb + kk] : 0.f;
      }
    }
#pragma unroll
    for (int kk = 0; kk < 16; ++kk) {
      float4 av = *(const float4*)&As[kk][ty * 4];
      float4 bv = *(const float4*)&Bs[kk][tx * 4];
      acc[0][0] += av.x * bv.x; acc[0][1] += av.x * bv.y; acc[0][2] += av.x * bv.z; acc[0][3] += av.x * bv.w;
      acc[1][0] += av.y * bv.x; acc[1][1] += av.y * bv.y; acc[1][2] += av.y * bv.z; acc[1][3] += av.y * bv.w;
      acc[2][0] += av.z * bv.x; acc[2][1] += av.z * bv.y; acc[2][2] += av.z * bv.z; acc[2][3] += av.z * bv.w;
      acc[3][0] += av.w * bv.x; acc[3][1] += av.w * bv.y; acc[3][2] += av.w * bv.z; acc[3][3] += av.w * bv.w;
    }
    __syncthreads();
  }
  size_t base = (size_t)sk * M * N;
#pragma unroll
  for (int r = 0; r < 4; ++r) {
    int i = bi + ty * 4 + r;
    if (i >= M) continue;
#pragma unroll
    for (int c = 0; c < 4; ++c) {
      int j = bj + tx * 4 + c;
      if (j < N) P[base + (size_t)i * N + j] = acc[r][c];
    }
  }
}

// ---------------------------------------------------------------------------
// Reduce split-K partials (setup only). C = sum (and C2 = sum if C2 != null)
__global__ __launch_bounds__(256) void reduce_sk_k(
    const float* __restrict__ P, float* __restrict__ C, float* __restrict__ C2,
    long long total, long long stride, int SK) {
  long long gid = (long long)blockIdx.x * 256 + threadIdx.x;
  if (gid >= total) return;
  float s = 0.f;
  for (int k = 0; k < SK; ++k) s += P[(size_t)k * stride + gid];
  C[gid] = s;
  if (C2) C2[gid] = s;
}

// ---------------------------------------------------------------------------
// Pack conv2-type weights fp32 [co][ci][3][3] -> fp16 [slot][tap][co][ci].
__global__ __launch_bounds__(256) void pack_w_k(const float* __restrict__ w0,
                                                const float* __restrict__ w1,
                                                const float* __restrict__ w2,
                                                const float* __restrict__ w3,
                                                __half* __restrict__ wp, int layers) {
  int gid = blockIdx.x * 256 + threadIdx.x;
  int total = layers * 4 * 9216;
  if (gid >= total) return;
  int slot = gid / 9216, r = gid - slot * 9216;
  int n = slot >> 2, which = slot & 3;
  int tap = r / 1024, r2 = r - tap * 1024;
  int co = r2 >> 5, ci = r2 & 31;
  const float* src = (which == 0) ? w0 : (which == 1) ? w1 : (which == 2) ? w2 : w3;
  wp[gid] = __float2half(src[n * 9216 + (co * 32 + ci) * 9 + tap]);
}

// ---------------------------------------------------------------------------
// Pack AtA fp32 [1089][1089] -> fp16 [1120][1120] zero-padded.
__global__ __launch_bounds__(256) void pack_ata_k(const float* __restrict__ A,
                                                  __half* __restrict__ Ah) {
  int gid = blockIdx.x * 256 + threadIdx.x;
  if (gid >= KPAD * KPAD) return;
  int r = gid / KPAD, c = gid - r * KPAD;
  Ah[gid] = __float2half((r < NBB && c < NBB) ? A[(size_t)r * NBB + c] : 0.f);
}

// ---------------------------------------------------------------------------
// X-update via MFMA fp16: img[unblk(i,j)] = T[i,j] - step*dot(Th[i,:],Ah[j,:]) + step*X0[i,j]
// grid (35, 16), 256 thr = 4 waves, each wave a 16x16 quadrant of the 32x32 tile.
__global__ __launch_bounds__(256) void xupdate_mfma_k(
    const __half* __restrict__ Th, const __half* __restrict__ Ah,
    const float* __restrict__ T, const float* __restrict__ X0,
    float* __restrict__ img, const float* __restrict__ step_ptr) {
  int lane = threadIdx.x & 63;
  int wave = threadIdx.x >> 6;
  int m16 = lane & 15, kg = lane >> 4;
  int i0 = blockIdx.y * 32 + (wave >> 1) * 16;
  int j0 = blockIdx.x * 32 + (wave & 1) * 16;
  const f16x8* ap = (const f16x8*)(Th + (size_t)(i0 + m16) * KPAD + kg * 8);
  const f16x8* bp = (const f16x8*)(Ah + (size_t)(j0 + m16) * KPAD + kg * 8);
  f32x4 acc = {0.f, 0.f, 0.f, 0.f};
  f16x8 a = ap[0], b = bp[0];
#pragma unroll 2
  for (int s = 1; s < 35; ++s) {      // k advances 32 halves = 4 f16x8 per step
    f16x8 an = ap[s * 4];
    f16x8 bn = bp[s * 4];
    acc = __builtin_amdgcn_mfma_f32_16x16x32_f16(a, b, acc, 0, 0, 0);
    a = an; b = bn;
  }
  acc = __builtin_amdgcn_mfma_f32_16x16x32_f16(a, b, acc, 0, 0, 0);
  float st = step_ptr[0];
  int j = j0 + m16;
  if (j < NBB) {
    int pi = j / BLKSZ, pj = j - pi * BLKSZ;
#pragma unroll
    for (int r = 0; r < 4; ++r) {
      int i = i0 + kg * 4 + r;
      size_t idx = (size_t)i * NBB + j;
      float v = T[idx] - st * acc[r] + st * X0[idx];
      int li = i >> 6, hi = (i >> 3) & 7, si = i & 7;
      img[((size_t)si * IMW + hi * BLKSZ + pi) * IMW + li * BLKSZ + pj] = v;
    }
  }
}

// ---------------------------------------------------------------------------
// Zero halo border of ONE NHWC(32) fp16 buffer.
__global__ __launch_bounds__(256) void zero_borders1_k(__half* __restrict__ a,
                                                       int nimg, int H, int W) {
  int Wp = W + 2, Hp = H + 2;
  int perim = 2 * Wp + 2 * H;
  int gid = blockIdx.x * 256 + threadIdx.x;
  int total = nimg * perim;
  if (gid >= total) return;
  int img = gid / perim, k = gid - img * perim;
  int row, col;
  if (k < Wp)            { row = 0;      col = k; }
  else if (k < 2 * Wp)   { row = Hp - 1; col = k - Wp; }
  else { int k2 = k - 2 * Wp; row = 1 + (k2 >> 1); col = (k2 & 1) ? (Wp - 1) : 0; }
  size_t off = ((size_t)(img * Hp + row) * Wp + col) * 32;
  float4 z = {0.f, 0.f, 0.f, 0.f};
  float4* pa = (float4*)(a + off);
#pragma unroll
  for (int q = 0; q < 4; ++q) pa[q] = z;
}

// ---------------------------------------------------------------------------
// conv1: planar fp32 -> padded NHWC fp16, relu(conv+bias). Extended grid:
// border threads write zeros.
__global__ __launch_bounds__(256) void conv1_k(const float* __restrict__ in,
                                               __half* __restrict__ out,
                                               const float* __restrict__ w,
                                               const float* __restrict__ b,
                                               int nimg, int H, int W) {
  __shared__ float wl[9][32];
  __shared__ float bl[32];
  int tid = threadIdx.x;
  for (int t = tid; t < 288; t += 256) {
    int co = t / 9, tap = t - co * 9;
    wl[tap][co] = w[t];
  }
  if (tid < 32) bl[tid] = b[tid];
  __syncthreads();
  int Hp = H + 2, Wp = W + 2;
  int gid = blockIdx.x * 256 + tid;
  if (gid >= nimg * Hp * Wp) return;
  int img = gid / (Hp * Wp);
  int rem = gid - img * (Hp * Wp);
  int yy = rem / Wp, xx = rem - yy * Wp;
  size_t ob = ((size_t)(img * Hp + yy) * Wp + xx) * 32;
  if (yy == 0 || yy == Hp - 1 || xx == 0 || xx == Wp - 1) {
    float4 z = {0.f, 0.f, 0.f, 0.f};
#pragma unroll
    for (int q = 0; q < 4; ++q) *(float4*)(out + ob + 8 * q) = z;
    return;
  }
  int y = yy - 1, x = xx - 1;
  float acc[32];
#pragma unroll
  for (int c = 0; c < 32; ++c) acc[c] = bl[c];
  const float* ip = in + (size_t)img * H * W;
#pragma unroll
  for (int ty = 0; ty < 3; ++ty)
#pragma unroll
    for (int tx = 0; tx < 3; ++tx) {
      int yv = y + ty - 1, xv = x + tx - 1;
      if (yv >= 0 && yv < H && xv >= 0 && xv < W) {
        float v = ip[(size_t)yv * W + xv];
        const float* wp = &wl[ty * 3 + tx][0];
#pragma unroll
        for (int q = 0; q < 8; ++q) {
          float4 wv = *(const float4*)(wp + q * 4);
          acc[q * 4 + 0] += v * wv.x; acc[q * 4 + 1] += v * wv.y;
          acc[q * 4 + 2] += v * wv.z; acc[q * 4 + 3] += v * wv.w;
        }
      }
    }
  __half2* op = (__half2*)(out + ob);
#pragma unroll
  for (int c2 = 0; c2 < 16; ++c2)
    op[c2] = __floats2half2_rn(fmaxf(acc[2 * c2], 0.f), fmaxf(acc[2 * c2 + 1], 0.f));
}

// ---------------------------------------------------------------------------
// conv2 via MFMA, y-marching, BOTH co-halves per wave (A-ring shared, 18 MFMA
// per 3 loads). Wave owns (img, x-tile, y-chunk).
__global__ __launch_bounds__(256) void conv2_mfma_k(const __half* __restrict__ in,
                                                    __half* __restrict__ out,
                                                    const __half* __restrict__ wp,
                                                    const float* __restrict__ bias,
                                                    int nimg, int H, int W, int CH) {
  int ntx = (W + 15) >> 4;
  int nch = (H + CH - 1) / CH;
  int wid = blockIdx.x * 4 + (threadIdx.x >> 6);
  int total = nimg * ntx * nch;
  if (wid >= total) return;
  int lane = threadIdx.x & 63;
  int m16 = lane & 15, kg = lane >> 4;
  int yc = wid % nch; int t = wid / nch;
  int xt = t % ntx; int img = t / ntx;
  int Wp = W + 2, Hp = H + 2, Hpm1 = Hp - 1;
  const __half* wqA = wp + m16 * 32 + kg * 8;
  const __half* wqB = wp + (16 + m16) * 32 + kg * 8;
  f16x8 bA0 = *(const f16x8*)(wqA + 0 * 1024), bB0 = *(const f16x8*)(wqB + 0 * 1024);
  f16x8 bA1 = *(const f16x8*)(wqA + 1 * 1024), bB1 = *(const f16x8*)(wqB + 1 * 1024);
  f16x8 bA2 = *(const f16x8*)(wqA + 2 * 1024), bB2 = *(const f16x8*)(wqB + 2 * 1024);
  f16x8 bA3 = *(const f16x8*)(wqA + 3 * 1024), bB3 = *(const f16x8*)(wqB + 3 * 1024);
  f16x8 bA4 = *(const f16x8*)(wqA + 4 * 1024), bB4 = *(const f16x8*)(wqB + 4 * 1024);
  f16x8 bA5 = *(const f16x8*)(wqA + 5 * 1024), bB5 = *(const f16x8*)(wqB + 5 * 1024);
  f16x8 bA6 = *(const f16x8*)(wqA + 6 * 1024), bB6 = *(const f16x8*)(wqB + 6 * 1024);
  f16x8 bA7 = *(const f16x8*)(wqA + 7 * 1024), bB7 = *(const f16x8*)(wqB + 7 * 1024);
  f16x8 bA8 = *(const f16x8*)(wqA + 8 * 1024), bB8 = *(const f16x8*)(wqB + 8 * 1024);
  float bvA = bias[m16], bvB = bias[16 + m16];
  int x0 = xt << 4;
  int y1 = yc * CH + 1;
  int y2 = y1 + CH - 1; if (y2 > H) y2 = H;
  int c0 = x0 + m16;     if (c0 > W + 1) c0 = W + 1; c0 *= 32;
  int c1 = x0 + m16 + 1; if (c1 > W + 1) c1 = W + 1; c1 *= 32;
  int c2 = x0 + m16 + 2; if (c2 > W + 1) c2 = W + 1; c2 *= 32;
  size_t ibase = (size_t)img * Hp;

#define LOADROW(row, d0, d1, d2) { int rr = (row); if (rr > Hpm1) rr = Hpm1;    \
    const __half* rp = in + (ibase + rr) * (size_t)Wp * 32 + kg * 8;            \
    d0 = *(const f16x8*)(rp + c0); d1 = *(const f16x8*)(rp + c1);               \
    d2 = *(const f16x8*)(rp + c2); }

#define CITER(yo, A0_,A1_,A2_, B0_,B1_,B2_, C0_,C1_,C2_, P0_,P1_,P2_) {         \
    LOADROW((yo) + 3, P0_, P1_, P2_);                                           \
    f32x4 aA0 = {0.f,0.f,0.f,0.f}, aA1 = {0.f,0.f,0.f,0.f};                     \
    f32x4 aB0 = {0.f,0.f,0.f,0.f}, aB1 = {0.f,0.f,0.f,0.f};                     \
    aA0 = __builtin_amdgcn_mfma_f32_16x16x32_f16(A0_, bA0, aA0, 0, 0, 0);       \
    aB0 = __builtin_amdgcn_mfma_f32_16x16x32_f16(A0_, bB0, aB0, 0, 0, 0);       \
    aA1 = __builtin_amdgcn_mfma_f32_16x16x32_f16(A1_, bA1, aA1, 0, 0, 0);       \
    aB1 = __builtin_amdgcn_mfma_f32_16x16x32_f16(A1_, bB1, aB1, 0, 0, 0);       \
    aA0 = __builtin_amdgcn_mfma_f32_16x16x32_f16(A2_, bA2, aA0, 0, 0, 0);       \
    aB0 = __builtin_amdgcn_mfma_f32_16x16x32_f16(A2_, bB2, aB0, 0, 0, 0);       \
    aA1 = __builtin_amdgcn_mfma_f32_16x16x32_f16(B0_, bA3, aA1, 0, 0, 0);       \
    aB1 = __builtin_amdgcn_mfma_f32_16x16x32_f16(B0_, bB3, aB1, 0, 0, 0);       \
    aA0 = __builtin_amdgcn_mfma_f32_16x16x32_f16(B1_, bA4, aA0, 0, 0, 0);       \
    aB0 = __builtin_amdgcn_mfma_f32_16x16x32_f16(B1_, bB4, aB0, 0, 0, 0);       \
    aA1 = __builtin_amdgcn_mfma_f32_16x16x32_f16(B2_, bA5, aA1, 0, 0, 0);       \
    aB1 = __builtin_amdgcn_mfma_f32_16x16x32_f16(B2_, bB5, aB1, 0, 0, 0);       \
    aA0 = __builtin_amdgcn_mfma_f32_16x16x32_f16(C0_, bA6, aA0, 0, 0, 0);       \
    aB0 = __builtin_amdgcn_mfma_f32_16x16x32_f16(C0_, bB6, aB0, 0, 0, 0);       \
    aA1 = __builtin_amdgcn_mfma_f32_16x16x32_f16(C1_, bA7, aA1, 0, 0, 0);       \
    aB1 = __builtin_amdgcn_mfma_f32_16x16x32_f16(C1_, bB7, aB1, 0, 0, 0);       \
    aA0 = __builtin_amdgcn_mfma_f32_16x16x32_f16(C2_, bA8, aA0, 0, 0, 0);       \
    aB0 = __builtin_amdgcn_mfma_f32_16x16x32_f16(C2_, bB8, aB0, 0, 0, 0);       \
    __half* op = out + (ibase + (yo)) * (size_t)Wp * 32;                        \
    _Pragma("unroll")                                                           \
    for (int r = 0; r < 4; ++r) { int xo = x0 + kg * 4 + r;                     \
      if (xo < W) { __half* o2 = op + (xo + 1) * 32;                            \
        o2[m16]      = __float2half(fmaxf(aA0[r] + aA1[r] + bvA, 0.f));         \
        o2[16 + m16] = __float2half(fmaxf(aB0[r] + aB1[r] + bvB, 0.f)); } } }

  f16x8 A0,A1,A2,B0,B1,B2,C0,C1,C2,D0,D1,D2,E0,E1,E2;
  LOADROW(y1 - 1, A0, A1, A2);
  LOADROW(y1,     B0, B1, B2);
  LOADROW(y1 + 1, C0, C1, C2);
  LOADROW(y1 + 2, D0, D1, D2);
  int yo = y1;
  for (; yo + 4 <= y2; yo += 5) {
    CITER(yo,     A0,A1,A2, B0,B1,B2, C0,C1,C2, E0,E1,E2);
    CITER(yo + 1, B0,B1,B2, C0,C1,C2, D0,D1,D2, A0,A1,A2);
    CITER(yo + 2, C0,C1,C2, D0,D1,D2, E0,E1,E2, B0,B1,B2);
    CITER(yo + 3, D0,D1,D2, E0,E1,E2, A0,A1,A2, C0,C1,C2);
    CITER(yo + 4, E0,E1,E2, A0,A1,A2, B0,B1,B2, D0,D1,D2);
  }
  if (yo <= y2) { CITER(yo, A0,A1,A2, B0,B1,B2, C0,C1,C2, E0,E1,E2); ++yo; }
  if (yo <= y2) { CITER(yo, B0,B1,B2, C0,C1,C2, D0,D1,D2, A0,A1,A2); ++yo; }
  if (yo <= y2) { CITER(yo, C0,C1,C2, D0,D1,D2, E0,E1,E2, B0,B1,B2); ++yo; }
  if (yo <= y2) { CITER(yo, D0,D1,D2, E0,E1,E2, A0,A1,A2, C0,C1,C2); ++yo; }
#undef CITER
#undef LOADROW
}

// ---------------------------------------------------------------------------
// conv4: padded NHWC fp16 -> fp32 via fdot2. out = src + sign*conv.
// perm=1: blockify write.
__global__ __launch_bounds__(256) void conv4_k(const __half* __restrict__ in,
                                               float* __restrict__ out,
                                               const float* __restrict__ w,
                                               const float* __restrict__ src,
                                               int nimg, int H, int W, float sign, int perm) {
  __shared__ f16x2 wl[9][16];   // [tap][ci-pair]
  int tid = threadIdx.x;
  for (int t = tid; t < 144; t += 256) {
    int tap = t % 9, c2 = t / 9;
    f16x2 h;
    h[0] = (_Float16)w[(2 * c2) * 9 + tap];
    h[1] = (_Float16)w[(2 * c2 + 1) * 9 + tap];
    wl[tap][c2] = h;
  }
  __syncthreads();
  int gid = blockIdx.x * 256 + tid;
  if (gid >= nimg * H * W) return;
  int img = gid / (H * W);
  int rem = gid - img * H * W;
  int y = rem / W, x = rem - y * W;
  int Wp = W + 2;
  float acc = 0.f;
#pragma unroll
  for (int ty = 0; ty < 3; ++ty)
#pragma unroll
    for (int tx = 0; tx < 3; ++tx) {
      const f16x8* ip = (const f16x8*)(in + ((size_t)(img * (H + 2) + y + ty) * Wp + x + tx) * 32);
      const f16x2* wpt = &wl[ty * 3 + tx][0];
#pragma unroll
      for (int q = 0; q < 4; ++q) {
        f16x8 v = ip[q];
        const f16x2* pv = (const f16x2*)&v;
#pragma unroll
        for (int e = 0; e < 4; ++e) acc = dot2f(pv[e], wpt[q * 4 + e], acc);
      }
    }
  float val = src[gid] + sign * acc;
  if (perm) {
    int h = y / BLKSZ, i = y - h * BLKSZ;
    int l = x / BLKSZ, j = x - l * BLKSZ;
    out[(size_t)(l * 64 + h * 8 + img) * NBB + i * BLKSZ + j] = val;
  } else {
    out[gid] = val;
  }
}

// ---------------------------------------------------------------------------
// FUSED denoise CNN: one workgroup (4 waves, 256 thr) per 33x33 image; both
// padded 35x35x32 fp16 planes in LDS. Emits T = X + noise (fp32 + fp16 padded).
// 256 threads, NOT 512: at 512 the allocator caps VGPR at 128 -> scratch spill
// (133MB HBM traffic, measured rounds 10 and 12); launch_bounds(512,2) does
// NOT lift the cap. 256/4-wave runs at VGPR 188, FETCH 1.4MB, 86us.
__global__ __launch_bounds__(256) void denoise_fused_k(
    const float* __restrict__ X, float* __restrict__ T, __half* __restrict__ Th,
    const float* __restrict__ w1, const float* __restrict__ b1,
    const __half* __restrict__ wp2, const float* __restrict__ b2,
    const __half* __restrict__ wp3, const float* __restrict__ b3,
    const float* __restrict__ w4) {
  __shared__ __align__(16) __half Abuf[35 * 35 * 32];   // 78400 B
  __shared__ __align__(16) __half Bbuf[35 * 35 * 32];   // 78400 B
  __shared__ float wl1[9][32];
  __shared__ f16x2 wl4h[9][16];
  __shared__ float bl1[32];
  int tid = threadIdx.x;
  int img = blockIdx.x;
  int wave = tid >> 6, lane = tid & 63;
  int m16 = lane & 15, kg = lane >> 4;

  for (int t = tid; t < 288; t += 256) {
    int c = t / 9, tap = t - c * 9;
    wl1[tap][c] = w1[t];
  }
  for (int t = tid; t < 144; t += 256) {
    int tap = t % 9, c2 = t / 9;
    f16x2 h;
    h[0] = (_Float16)w4[(2 * c2) * 9 + tap];
    h[1] = (_Float16)w4[(2 * c2 + 1) * 9 + tap];
    wl4h[tap][c2] = h;
  }
  if (tid < 32) bl1[tid] = b1[tid];
  // stage X image into Bbuf-front (dead after conv1)
  float* Xs = (float*)Bbuf;
  const float* Xg = X + (size_t)img * NBB;
  for (int t = tid; t < NBB; t += 256) Xs[t] = Xg[t];
  __syncthreads();

  // ---- phase 1: conv1  Xs -> Abuf (padded, borders zeroed) ----
  for (int cell = tid; cell < 1225; cell += 256) {
    int yy = cell / 35, xx = cell - yy * 35;
    __half* oc = Abuf + cell * 32;
    if (yy == 0 || yy == 34 || xx == 0 || xx == 34) {
      f16x8 hz = {};
#pragma unroll
      for (int q = 0; q < 4; ++q) *(f16x8*)(oc + 8 * q) = hz;
      continue;
    }
    int y = yy - 1, x = xx - 1;
    float acc[32];
#pragma unroll
    for (int c = 0; c < 32; ++c) acc[c] = bl1[c];
#pragma unroll
    for (int dy = 0; dy < 3; ++dy)
#pragma unroll
      for (int dx = 0; dx < 3; ++dx) {
        int yv = y + dy - 1, xv = x + dx - 1;
        if (yv >= 0 && yv < 33 && xv >= 0 && xv < 33) {
          float v = Xs[yv * 33 + xv];
          const float* wp = &wl1[dy * 3 + dx][0];
#pragma unroll
          for (int q = 0; q < 8; ++q) {
            float4 wv = *(const float4*)(wp + q * 4);
            acc[q * 4 + 0] += v * wv.x; acc[q * 4 + 1] += v * wv.y;
            acc[q * 4 + 2] += v * wv.z; acc[q * 4 + 3] += v * wv.w;
          }
        }
      }
    __half2* op = (__half2*)oc;
#pragma unroll
    for (int c2 = 0; c2 < 16; ++c2)
      op[c2] = __floats2half2_rn(fmaxf(acc[2 * c2], 0.f), fmaxf(acc[2 * c2 + 1], 0.f));
  }
  __syncthreads();

  // ---- conv2 over LDS: 12 jobs = cohalf(2) x xt(3) x yh(2 chunks of 17) ----
#define CONV2LDS(SRC, DST, WPTR, BPTR) {                                        \
  _Pragma("unroll 1")                                                           \
  for (int jid = wave; jid < 12; jid += 4) {                                    \
    int cohalf = jid & 1;                                                       \
    int xt = (jid >> 1) % 3;                                                    \
    int yh = jid / 6;                                                           \
    const __half* wq = WPTR + (cohalf * 16 + m16) * 32 + kg * 8;                \
    f16x8 bfr0 = *(const f16x8*)(wq + 0 * 1024);                                \
    f16x8 bfr1 = *(const f16x8*)(wq + 1 * 1024);                                \
    f16x8 bfr2 = *(const f16x8*)(wq + 2 * 1024);                                \
    f16x8 bfr3 = *(const f16x8*)(wq + 3 * 1024);                                \
    f16x8 bfr4 = *(const f16x8*)(wq + 4 * 1024);                                \
    f16x8 bfr5 = *(const f16x8*)(wq + 5 * 1024);                                \
    f16x8 bfr6 = *(const f16x8*)(wq + 6 * 1024);                                \
    f16x8 bfr7 = *(const f16x8*)(wq + 7 * 1024);                                \
    f16x8 bfr8 = *(const f16x8*)(wq + 8 * 1024);                                \
    float bv = BPTR[cohalf * 16 + m16];                                         \
    int x0 = xt << 4;                                                           \
    int y1 = 1 + yh * 17;                                                       \
    int y2 = yh ? 33 : 17;                                                      \
    int c0 = x0 + m16;     if (c0 > 34) c0 = 34; c0 *= 32;                      \
    int c1 = x0 + m16 + 1; if (c1 > 34) c1 = 34; c1 *= 32;                      \
    int c2 = x0 + m16 + 2; if (c2 > 34) c2 = 34; c2 *= 32;                      \
    int cohalf16 = cohalf * 16;                                                 \
    f16x8 A0,A1,A2,B0,B1,B2,C0,C1,C2,D0,D1,D2,E0,E1,E2;                         \
    LROW(SRC, y1 - 1, A0, A1, A2);                                              \
    LROW(SRC, y1,     B0, B1, B2);                                              \
    LROW(SRC, y1 + 1, C0, C1, C2);                                              \
    LROW(SRC, y1 + 2, D0, D1, D2);                                              \
    int yo = y1;                                                                \
    for (; yo + 4 <= y2; yo += 5) {                                             \
      CIT(SRC, DST, yo,     A0,A1,A2, B0,B1,B2, C0,C1,C2, E0,E1,E2);            \
      CIT(SRC, DST, yo + 1, B0,B1,B2, C0,C1,C2, D0,D1,D2, A0,A1,A2);            \
      CIT(SRC, DST, yo + 2, C0,C1,C2, D0,D1,D2, E0,E1,E2, B0,B1,B2);            \
      CIT(SRC, DST, yo + 3, D0,D1,D2, E0,E1,E2, A0,A1,A2, C0,C1,C2);            \
      CIT(SRC, DST, yo + 4, E0,E1,E2, A0,A1,A2, B0,B1,B2, D0,D1,D2);            \
    }                                                                           \
    if (yo <= y2) { CIT(SRC, DST, yo, A0,A1,A2, B0,B1,B2, C0,C1,C2, E0,E1,E2); ++yo; } \
    if (yo <= y2) { CIT(SRC, DST, yo, B0,B1,B2, C0,C1,C2, D0,D1,D2, A0,A1,A2); ++yo; } \
    if (yo <= y2) { CIT(SRC, DST, yo, C0,C1,C2, D0,D1,D2, E0,E1,E2, B0,B1,B2); ++yo; } \
    if (yo <= y2) { CIT(SRC, DST, yo, D0,D1,D2, E0,E1,E2, A0,A1,A2, C0,C1,C2); ++yo; } \
  } }

#define LROW(SRC, row, d0, d1, d2) { int rr = (row); if (rr > 34) rr = 34;      \
    const __half* rp = SRC + rr * 35 * 32 + kg * 8;                             \
    d0 = *(const f16x8*)(rp + c0); d1 = *(const f16x8*)(rp + c1);               \
    d2 = *(const f16x8*)(rp + c2); }

#define CIT(SRC, DST, yo, A0_,A1_,A2_, B0_,B1_,B2_, C0_,C1_,C2_, P0_,P1_,P2_) { \
    LROW(SRC, (yo) + 3, P0_, P1_, P2_);                                         \
    f32x4 a0 = {0.f, 0.f, 0.f, 0.f}, a1 = {0.f, 0.f, 0.f, 0.f};                 \
    a0 = __builtin_amdgcn_mfma_f32_16x16x32_f16(A0_, bfr0, a0, 0, 0, 0);        \
    a1 = __builtin_amdgcn_mfma_f32_16x16x32_f16(A1_, bfr1, a1, 0, 0, 0);        \
    a0 = __builtin_amdgcn_mfma_f32_16x16x32_f16(A2_, bfr2, a0, 0, 0, 0);        \
    a1 = __builtin_amdgcn_mfma_f32_16x16x32_f16(B0_, bfr3, a1, 0, 0, 0);        \
    a0 = __builtin_amdgcn_mfma_f32_16x16x32_f16(B1_, bfr4, a0, 0, 0, 0);        \
    a1 = __builtin_amdgcn_mfma_f32_16x16x32_f16(B2_, bfr5, a1, 0, 0, 0);        \
    a0 = __builtin_amdgcn_mfma_f32_16x16x32_f16(C0_, bfr6, a0, 0, 0, 0);        \
    a1 = __builtin_amdgcn_mfma_f32_16x16x32_f16(C1_, bfr7, a1, 0, 0, 0);        \
    a0 = __builtin_amdgcn_mfma_f32_16x16x32_f16(C2_, bfr8, a0, 0, 0, 0);        \
    _Pragma("unroll")                                                           \
    for (int r = 0; r < 4; ++r) { int xo = x0 + kg * 4 + r;                     \
      if (xo < 33) DST[(yo) * 35 * 32 + (xo + 1) * 32 + cohalf16 + m16] =       \
        __float2half(fmaxf(a0[r] + a1[r] + bv, 0.f)); } }

  // ---- phase 2: zero Bbuf borders, then conv2#1  Abuf -> Bbuf ----
  {
    f16x8 hz = {};
    for (int t = tid; t < 544; t += 256) {
      int ci = t >> 2, q = t & 3;
      int cell;
      if (ci < 35)       cell = ci;
      else if (ci < 70)  cell = 34 * 35 + (ci - 35);
      else if (ci < 103) cell = (ci - 70 + 1) * 35;
      else               cell = (ci - 103 + 1) * 35 + 34;
      *(f16x8*)(Bbuf + cell * 32 + q * 8) = hz;
    }
  }
  __syncthreads();
  CONV2LDS(Abuf, Bbuf, wp2, b2);
  __syncthreads();

  // ---- phase 3: conv2#2  Bbuf -> Abuf (interior; Abuf halo still zero) ----
  CONV2LDS(Bbuf, Abuf, wp3, b3);
  __syncthreads();
#undef CIT
#undef LROW
#undef CONV2LDS

  // ---- phase 4: conv4 via fdot2  Abuf -> T = X + noise (fp32 + fp16 copy) ----
  float* Tg = T + (size_t)img * NBB;
  __half* Thg = Th + (size_t)img * KPAD;
  for (int p = tid; p < NBB; p += 256) {
    int y = p / 33, x = p - y * 33;
    float acc = 0.f;
#pragma unroll
    for (int dy = 0; dy < 3; ++dy)
#pragma unroll
      for (int dx = 0; dx < 3; ++dx) {
        const f16x8* ip = (const f16x8*)(Abuf + ((y + dy) * 35 + x + dx) * 32);
        const f16x2* wpt = &wl4h[dy * 3 + dx][0];
#pragma unroll
        for (int q = 0; q < 4; ++q) {
          f16x8 v = ip[q];
          const f16x2* pv = (const f16x2*)&v;
#pragma unroll
          for (int e = 0; e < 4; ++e) acc = dot2f(pv[e], wpt[q * 4 + e], acc);
        }
      }
    float val = Xg[p] + acc;
    Tg[p] = val;
    Thg[p] = __float2half(val);
  }
  for (int t = tid; t < KPAD - NBB; t += 256)
    Thg[NBB + t] = __float2half(0.f);
}

// ---------------------------------------------------------------------------
static inline int cdiv(int a, int b) { return (a + b - 1) / b; }

extern "C" void kernel_launch(void* const* d_in, const int* in_sizes, int n_in,
                              void* d_out, int out_size, void* d_ws, size_t ws_size,
                              hipStream_t stream) {
  const float* d_inputs = (const float*)d_in[0];
  const float* d_A      = (const float*)d_in[1];
  const float* d_Q      = (const float*)d_in[2];
  const float* d_steps  = (const float*)d_in[3];
  const float* den_w1 = (const float*)d_in[4];
  const float* den_b1 = (const float*)d_in[5];
  const float* den_b2 = (const float*)d_in[7];
  const float* den_b3 = (const float*)d_in[9];
  const float* den_w4 = (const float*)d_in[10];
  const float* deb_w1 = (const float*)d_in[11];
  const float* deb_b1 = (const float*)d_in[12];
  const float* deb_b2 = (const float*)d_in[14];
  const float* deb_b3 = (const float*)d_in[16];
  const float* deb_w4 = (const float*)d_in[17];

  int layers = in_sizes[3];                 // 5
  int M      = in_sizes[1] / NBB;           // 272
  int S      = in_sizes[0] / (IMW * IMW);   // 8
  int N      = 64 * S;                      // 512

  // ---- workspace layout ----
  float* ws    = (float*)d_ws;
  float* AtA   = ws;                           // 1089*1089 (pad 1185936)
  float* X     = AtA + 1185936;                // [N][1089]
  float* T     = X + (size_t)N * NBB;          // [N][1089]
  float* X0    = T + (size_t)N * NBB;          // [N][1089]
  float* y2    = X0 + (size_t)N * NBB;         // [N][M]
  float* img   = y2 + (size_t)N * M;           // [S][264][264]
  float* Pbuf  = img + (size_t)S * IMW * IMW;  // split-K partials (setup)
  __half* wph  = (__half*)(Pbuf + (size_t)8 * N * NBB);
  __half* buf1 = wph + (size_t)layers * 4 * 9216 + 2048;
  size_t bufElems = (size_t)S * 266 * 266 * 32;
  __half* buf2 = buf1 + bufElems;
  __half* Ah   = buf2 + bufElems;              // [1120][1120] fp16
  __half* Th   = Ah + (size_t)KPAD * KPAD;     // [N][1120] fp16

  dim3 blk(256);

  // ---- setup ----
  pack_w_k<<<cdiv(layers * 4 * 9216, 256), blk, 0, stream>>>(
      (const float*)d_in[6], (const float*)d_in[8], (const float*)d_in[13],
      (const float*)d_in[15], wph, layers);
  blockify_k<<<cdiv(N * NBB, 256), blk, 0, stream>>>(d_inputs, T, S);  // T = Xb

  gemm_nt_sk<<<dim3(cdiv(NBB, 64), cdiv(NBB, 64), 2), blk, 0, stream>>>(
      d_Q, d_Q, Pbuf, NBB, NBB, M, M, M, 2);
  reduce_sk_k<<<cdiv(NBB * NBB, 256), blk, 0, stream>>>(
      Pbuf, AtA, nullptr, (long long)NBB * NBB, (long long)NBB * NBB, 2);
  pack_ata_k<<<cdiv(KPAD * KPAD, 256), blk, 0, stream>>>(AtA, Ah);
  gemm_nt_sk<<<dim3(cdiv(M, 64), cdiv(N, 64), 8), blk, 0, stream>>>(
      T, d_A, Pbuf, N, M, NBB, NBB, NBB, 8);
  reduce_sk_k<<<cdiv(N * M, 256), blk, 0, stream>>>(
      Pbuf, y2, nullptr, (long long)N * M, (long long)N * M, 8);
  gemm_nt_sk<<<dim3(cdiv(NBB, 64), cdiv(N, 64), 4), blk, 0, stream>>>(
      y2, d_Q, Pbuf, N, NBB, M, M, M, 4);
  reduce_sk_k<<<cdiv(N * NBB, 256), blk, 0, stream>>>(
      Pbuf, X0, X, (long long)N * NBB, (long long)N * NBB, 4);

  const int CH_DEB = 12;
  int deb_jobs = S * cdiv(IMW, 16) * cdiv(IMW, CH_DEB);   // 8*17*22

  for (int n = 0; n < layers; ++n) {
    const float* stepp = d_steps + n;

    // ---- denoise CNN (fused, LDS-resident, 4 waves): T = X + noise ----
    denoise_fused_k<<<N, blk, 0, stream>>>(
        X, T, Th, den_w1 + n * 288, den_b1 + n * 32,
        wph + (size_t)(n * 4 + 0) * 9216, den_b2 + n * 32,
        wph + (size_t)(n * 4 + 1) * 9216, den_b3 + n * 32,
        den_w4 + n * 288);

    // ---- img = unblockify( T - step*(T@AtA) + step*X0 )  [MFMA fp16] ----
    xupdate_mfma_k<<<dim3(35, 16), blk, 0, stream>>>(
        Th, Ah, T, X0, img, stepp);

    // ---- deblock CNN on img ----
    zero_borders1_k<<<cdiv(S * (2 * 266 + 2 * 264), 256), blk, 0, stream>>>(
        buf2, S, IMW, IMW);
    conv1_k<<<cdiv(S * 266 * 266, 256), blk, 0, stream>>>(
        img, buf1, deb_w1 + n * 288, deb_b1 + n * 32, S, IMW, IMW);
    conv2_mfma_k<<<cdiv(deb_jobs, 4), blk, 0, stream>>>(
        buf1, buf2, wph + (size_t)(n * 4 + 2) * 9216, deb_b2 + n * 32, S, IMW, IMW, CH_DEB);
    conv2_mfma_k<<<cdiv(deb_jobs, 4), blk, 0, stream>>>(
        buf2, buf1, wph + (size_t)(n * 4 + 3) * 9216, deb_b3 + n * 32, S, IMW, IMW, CH_DEB);
    if (n < layers - 1) {
      conv4_k<<<cdiv(S * IMW * IMW, 256), blk, 0, stream>>>(
          buf1, X, deb_w4 + n * 288, img, S, IMW, IMW, -1.f, 1);
    } else {
      conv4_k<<<cdiv(S * IMW * IMW, 256), blk, 0, stream>>>(
          buf1, (float*)d_out, deb_w4 + n * 288, img, S, IMW, IMW, -1.f, 0);
    }
  }
}